// Round 1
// baseline (939.411 us; speedup 1.0000x reference)
//
#include <hip/hip_runtime.h>
#include <hip/hip_bf16.h>
#include <stdint.h>

typedef float  floatx4 __attribute__((ext_vector_type(4)));
typedef short  short8  __attribute__((ext_vector_type(8)));
typedef unsigned short u16;

#define DIM 512
#define NH 16
#define HD 32
#define WS 49           // window size (tokens)
#define NBW 2048        // number of windows
#define NWIN 4          // mask groups
#define M_TOTAL (NBW*WS)    // 100352
#define N_QKV (3*DIM)       // 1536

// ---------- helpers ----------
__device__ __forceinline__ u16 f2bf(float f) {
    uint32_t u = __float_as_uint(f);
    u += 0x7FFFu + ((u >> 16) & 1u);   // RNE
    return (u16)(u >> 16);
}

__device__ __forceinline__ void load_lds16(const u16* g, u16* l) {
    __builtin_amdgcn_global_load_lds(
        (const __attribute__((address_space(1))) unsigned int*)g,
        (__attribute__((address_space(3))) unsigned int*)l, 16, 0, 0);
}

// ---------- cast x fp32 -> bf16 (vectorized) ----------
__global__ void cast_x_kernel(const float* __restrict__ in, u16* __restrict__ out, int n4) {
    int i = blockIdx.x * blockDim.x + threadIdx.x;
    if (i >= n4) return;
    const float4 v = ((const float4*)in)[i];
    ushort4 o;
    o.x = f2bf(v.x); o.y = f2bf(v.y); o.z = f2bf(v.z); o.w = f2bf(v.w);
    ((ushort4*)out)[i] = o;
}

// ---------- transpose + cast weight [K=512][N] -> Bt [N][512] bf16 ----------
__global__ void transpose_cast_kernel(const float* __restrict__ in, u16* __restrict__ out,
                                      int N, int total) {
    int idx = blockIdx.x * blockDim.x + threadIdx.x;   // idx = n*512 + k
    if (idx >= total) return;
    int k = idx & (DIM - 1);
    int n = idx >> 9;
    out[idx] = f2bf(in[k * N + n]);
}

// ---------- padded bias+mask table, permuted for float4 lane loads ----------
__global__ void build_comb_kernel(const float* __restrict__ bias_table, const int* __restrict__ rel_idx,
                                  const float* __restrict__ mask, float* __restrict__ comb) {
    int idx = blockIdx.x * blockDim.x + threadIdx.x;
    if (idx >= NWIN * NH * 64 * 64) return;
    int c = idx & 3, jj = (idx >> 2) & 15, i = (idx >> 6) & 63, h = (idx >> 12) & 15, g = idx >> 16;
    int j = c * 16 + jj;
    float v = -1e30f;
    if (i < WS && j < WS)
        v = bias_table[rel_idx[i * WS + j] * NH + h] + mask[(g * WS + i) * WS + j];
    comb[idx] = v;
}

// ---------- 256x256 8-phase MFMA GEMM, C = A[M][K] * Bt[N][K]^T + bias ----------
// 512 threads = 8 waves (2M x 4N), per-wave output 128x64.
// LDS: 2 dbuf x {A,B} x 2 K-halves x [256 rows][32 elems] bf16 = 128 KiB.
// Dense 1KiB fragment reads (64B row pitch, 4 q-lanes cover each row) => no bank
// conflicts, no swizzle needed, global_load_lds linear dest stays legal.
// Counted vmcnt(4) at end of phases B/D (T4); raw s_barrier (no drain); setprio
// around each 16-MFMA cluster (T5); bijective XCD swizzle (T1).
#define STAGE_HALF(BASE, DST, Q, KH, KCOL)                                            \
    do {                                                                              \
        load_lds16((BASE) + (long)(s0 >> 2) * K + (KCOL) + (KH) * 32 + (s0 & 3) * 8,  \
                   &DST[Q][KH][s0 * 8]);                                              \
        load_lds16((BASE) + (long)(s1 >> 2) * K + (KCOL) + (KH) * 32 + (s1 & 3) * 8,  \
                   &DST[Q][KH][s1 * 8]);                                              \
    } while (0)

#define LDA4(P, MG, KH)                                                               \
    _Pragma("unroll")                                                                 \
    for (int mi = 0; mi < 4; ++mi)                                                    \
        af[mi] = *(const short8*)(&sA[P][KH][(wm + (MG) * 64 + mi * 16 + rr) * 32 + q4 * 8]);

#define LDB4(P, KH)                                                                   \
    _Pragma("unroll")                                                                 \
    for (int ni = 0; ni < 4; ++ni)                                                    \
        bf[ni] = *(const short8*)(&sB[P][KH][(wn + ni * 16 + rr) * 32 + q4 * 8]);

#define MFMA16(MG)                                                                    \
    _Pragma("unroll")                                                                 \
    for (int mi = 0; mi < 4; ++mi)                                                    \
        _Pragma("unroll")                                                             \
        for (int ni = 0; ni < 4; ++ni)                                                \
            acc[(MG) * 4 + mi][ni] = __builtin_amdgcn_mfma_f32_16x16x32_bf16(         \
                af[mi], bf[ni], acc[(MG) * 4 + mi][ni], 0, 0, 0);

template<bool OUT_BF16>
__global__ __launch_bounds__(512, 2) void gemm256_kernel(
    const u16* __restrict__ A, const u16* __restrict__ Bt,
    const float* __restrict__ bias, void* __restrict__ out, int N, int K)
{
    __shared__ __align__(16) u16 sA[2][2][256 * 32];
    __shared__ __align__(16) u16 sB[2][2][256 * 32];

    const int tid  = threadIdx.x;
    const int lane = tid & 63;
    const int w    = tid >> 6;
    const int rr   = lane & 15;
    const int q4   = lane >> 4;
    const int wm   = (w >> 2) * 128;
    const int wn   = (w & 3) * 64;

    // bijective XCD-aware swizzle (gridDim.x is a multiple of 8: 2352 / 784)
    const int nwg = gridDim.x;
    const int lid = (blockIdx.x & 7) * (nwg >> 3) + (blockIdx.x >> 3);
    const int GX  = N >> 8;
    const int bx  = lid % GX;
    const int by  = lid / GX;
    const long m0 = (long)by * 256;
    const long n0 = (long)bx * 256;

    const u16* Ab = A  + m0 * K;
    const u16* Bb = Bt + n0 * K;

    const int s0 = tid;
    const int s1 = tid + 512;

    floatx4 acc[8][4];
    const floatx4 z4 = {0.f, 0.f, 0.f, 0.f};
#pragma unroll
    for (int i = 0; i < 8; ++i)
#pragma unroll
        for (int j = 0; j < 4; ++j) acc[i][j] = z4;

    const int nk = K >> 6;

    // prologue: stage tile0, retire order [A.kh0, B.kh0, A.kh1, B.kh1]
#pragma unroll
    for (int kh = 0; kh < 2; ++kh) {
        STAGE_HALF(Ab, sA, 0, kh, 0);
        STAGE_HALF(Bb, sB, 0, kh, 0);
    }
    asm volatile("s_waitcnt vmcnt(4)" ::: "memory");   // kh0 halves resident
    __builtin_amdgcn_s_barrier();

    for (int it = 0; it < nk; ++it) {
        const int  p  = it & 1, q = p ^ 1;
        const int  kn = (it + 1) << 6;                 // next tile k-col
        const bool hn = (it + 1 < nk);
        short8 af[4], bf[4];

        // ---- phase A: kh0 x m-group0 ----
        if (hn) STAGE_HALF(Ab, sA, q, 0, kn);
        LDB4(p, 0)
        LDA4(p, 0, 0)
        __builtin_amdgcn_s_barrier();
        __builtin_amdgcn_s_setprio(1);
        MFMA16(0)
        __builtin_amdgcn_s_setprio(0);
        __builtin_amdgcn_s_barrier();

        // ---- phase B: kh0 x m-group1 ----
        if (hn) STAGE_HALF(Bb, sB, q, 0, kn);
        LDA4(p, 1, 0)
        __builtin_amdgcn_s_barrier();
        __builtin_amdgcn_s_setprio(1);
        MFMA16(1)
        __builtin_amdgcn_s_setprio(0);
        if (hn) { asm volatile("s_waitcnt vmcnt(4)" ::: "memory"); }   // this tile's kh1 resident
        else    { asm volatile("s_waitcnt vmcnt(0)" ::: "memory"); }
        __builtin_amdgcn_s_barrier();

        // ---- phase C: kh1 x m-group0 ----
        if (hn) STAGE_HALF(Ab, sA, q, 1, kn);
        LDB4(p, 1)
        LDA4(p, 0, 1)
        __builtin_amdgcn_s_barrier();
        __builtin_amdgcn_s_setprio(1);
        MFMA16(0)
        __builtin_amdgcn_s_setprio(0);
        __builtin_amdgcn_s_barrier();

        // ---- phase D: kh1 x m-group1 ----
        if (hn) STAGE_HALF(Bb, sB, q, 1, kn);
        LDA4(p, 1, 1)
        __builtin_amdgcn_s_barrier();
        __builtin_amdgcn_s_setprio(1);
        MFMA16(1)
        __builtin_amdgcn_s_setprio(0);
        if (hn) { asm volatile("s_waitcnt vmcnt(4)" ::: "memory"); }   // next tile's kh0 resident
        __builtin_amdgcn_s_barrier();
    }

    // epilogue
#pragma unroll
    for (int nf = 0; nf < 4; ++nf) {
        const long n = n0 + wn + nf * 16 + rr;
        const float bv = bias[n];
#pragma unroll
        for (int mf = 0; mf < 8; ++mf) {
            const long mrow = m0 + wm + mf * 16 + q4 * 4;
#pragma unroll
            for (int r = 0; r < 4; ++r) {
                const long m = mrow + r;
                const float v = acc[mf][nf][r] + bv;
                if (OUT_BF16) ((u16*)out)[m * N + n] = f2bf(v);
                else          ((float*)out)[m * N + n] = v;
            }
        }
    }
}

// ---------- attention v3: one wave per (window, head, 32-row half) ----------
__global__ __launch_bounds__(256, 4) void attn_kernel(
    const u16* __restrict__ qkv, const float* __restrict__ comb,
    u16* __restrict__ attn_out)
{
    const int w   = threadIdx.x >> 6;
    const int l   = threadIdx.x & 63;
    const int job = blockIdx.x * 4 + w;          // job = b*32 + h*2 + half
    const int b    = job >> 5;
    const int h    = (job >> 1) & 15;
    const int half = job & 1;
    const int row0 = half * 32;
    const int rr = l & 15;
    const int q4 = l >> 4;
    const int qk = q4 * 8;

    __shared__ __align__(16) u16 p_s[4][32 * 64];
    u16* ps = p_s[w];

    const u16* qg = qkv + (long)b * WS * N_QKV + h * HD;
    const u16* kg = qg + DIM;
    const u16* vg = qg + 2 * DIM;

    const short8 z8 = {0, 0, 0, 0, 0, 0, 0, 0};
    const floatx4 z4 = {0.f, 0.f, 0.f, 0.f};

    short8 af[2], bfr[4];
#pragma unroll
    for (int mi = 0; mi < 2; ++mi) {
        const int row = row0 + mi * 16 + rr;
        af[mi] = (row < WS) ? *(const short8*)(qg + (long)row * N_QKV + qk) : z8;
    }
#pragma unroll
    for (int ni = 0; ni < 4; ++ni) {
        const int row = ni * 16 + rr;
        bfr[ni] = (row < WS) ? *(const short8*)(kg + (long)row * N_QKV + qk) : z8;
    }

    short8 vf[2][2];
#pragma unroll
    for (int kk = 0; kk < 2; ++kk)
#pragma unroll
        for (int ni = 0; ni < 2; ++ni) {
            short8 t = z8;
            const int d = 2 * rr + ni;
#pragma unroll
            for (int j = 0; j < 8; ++j) {
                const int s = kk * 32 + qk + j;
                if (s < WS) t[j] = (short)vg[(long)s * N_QKV + d];
            }
            vf[kk][ni] = t;
        }
    short8 vones;
#pragma unroll
    for (int j = 0; j < 8; ++j) vones[j] = (short)0x3F80;

    floatx4 sc[2][4];
#pragma unroll
    for (int mi = 0; mi < 2; ++mi)
#pragma unroll
        for (int ni = 0; ni < 4; ++ni)
            sc[mi][ni] = __builtin_amdgcn_mfma_f32_16x16x32_bf16(af[mi], bfr[ni], z4, 0, 0, 0);

    const float4* cb4 = (const float4*)comb + ((long)((b & (NWIN - 1)) * NH + h)) * 1024;
    const float scale = 0.17677669529663689f;   // 32^-0.5
#pragma unroll
    for (int mi = 0; mi < 2; ++mi) {
#pragma unroll
        for (int r = 0; r < 4; ++r) {
            const int il = mi * 16 + q4 * 4 + r;       // local row 0..31
            const float4 cb = cb4[(row0 + il) * 16 + rr];
            float e0 = __expf(sc[mi][0][r] * scale + cb.x);
            float e1 = __expf(sc[mi][1][r] * scale + cb.y);
            float e2 = __expf(sc[mi][2][r] * scale + cb.z);
            float e3 = __expf(sc[mi][3][r] * scale + cb.w);
#pragma unroll
            for (int c = 0; c < 4; ++c) {
                const int col = c * 16 + rr;
                const int blk = (col >> 3) ^ (il & 7);
                const float ev = (c == 0) ? e0 : (c == 1) ? e1 : (c == 2) ? e2 : e3;
                ps[il * 64 + blk * 8 + (col & 7)] = f2bf(ev);
            }
        }
    }
    asm volatile("s_waitcnt lgkmcnt(0)" ::: "memory");

    floatx4 oacc[2][3];
#pragma unroll
    for (int mi = 0; mi < 2; ++mi) { oacc[mi][0] = z4; oacc[mi][1] = z4; oacc[mi][2] = z4; }
#pragma unroll
    for (int kk = 0; kk < 2; ++kk) {
        short8 pf[2];
#pragma unroll
        for (int mi = 0; mi < 2; ++mi) {
            const int i2 = mi * 16 + rr;
            pf[mi] = *(const short8*)(ps + i2 * 64 + (((4 * kk + q4) ^ (i2 & 7)) * 8));
        }
#pragma unroll
        for (int mi = 0; mi < 2; ++mi) {
            oacc[mi][0] = __builtin_amdgcn_mfma_f32_16x16x32_bf16(pf[mi], vf[kk][0], oacc[mi][0], 0, 0, 0);
            oacc[mi][1] = __builtin_amdgcn_mfma_f32_16x16x32_bf16(pf[mi], vf[kk][1], oacc[mi][1], 0, 0, 0);
            oacc[mi][2] = __builtin_amdgcn_mfma_f32_16x16x32_bf16(pf[mi], vones,     oacc[mi][2], 0, 0, 0);
        }
    }

#pragma unroll
    for (int mi = 0; mi < 2; ++mi) {
#pragma unroll
        for (int r = 0; r < 4; ++r) {
            const int ig = row0 + mi * 16 + q4 * 4 + r;
            if (ig < WS) {
                const float inv = 1.0f / oacc[mi][2][r];
                const uint32_t lo = f2bf(oacc[mi][0][r] * inv);
                const uint32_t hi = f2bf(oacc[mi][1][r] * inv);
                uint32_t* op = (uint32_t*)(attn_out + ((long)(b * WS + ig)) * DIM + h * HD);
                op[rr] = lo | (hi << 16);
            }
        }
    }
}

// ---------- launch ----------
extern "C" void kernel_launch(void* const* d_in, const int* in_sizes, int n_in,
                              void* d_out, int out_size, void* d_ws, size_t ws_size,
                              hipStream_t stream)
{
    const float* x          = (const float*)d_in[0];
    const float* mask       = (const float*)d_in[1];
    const float* w_qkv      = (const float*)d_in[2];
    const float* b_qkv      = (const float*)d_in[3];
    const float* w_proj     = (const float*)d_in[4];
    const float* b_proj     = (const float*)d_in[5];
    const float* bias_table = (const float*)d_in[6];
    const int*   rel_idx    = (const int*)d_in[7];
    float* out = (float*)d_out;

    char* ws = (char*)d_ws;
    u16* x_bf   = (u16*)ws;  ws += (size_t)M_TOTAL * DIM * 2;        // 102.8 MB (reused as attn_out)
    u16* wqkvT  = (u16*)ws;  ws += (size_t)N_QKV * DIM * 2;          // 1.5 MB
    u16* wprojT = (u16*)ws;  ws += (size_t)DIM * DIM * 2;            // 0.5 MB
    float* comb = (float*)ws; ws += (size_t)NWIN * NH * 64 * 64 * 4; // 1.0 MB
    u16* qkv    = (u16*)ws;  ws += (size_t)M_TOTAL * N_QKV * 2;      // 308.3 MB
    u16* attn_o = x_bf;   // alias: x_bf dead after GEMM1

    const int n4 = M_TOTAL * DIM / 4;
    cast_x_kernel<<<(n4 + 255) / 256, 256, 0, stream>>>(x, x_bf, n4);
    transpose_cast_kernel<<<(N_QKV * DIM + 255) / 256, 256, 0, stream>>>(w_qkv, wqkvT, N_QKV, N_QKV * DIM);
    transpose_cast_kernel<<<(DIM * DIM + 255) / 256, 256, 0, stream>>>(w_proj, wprojT, DIM, DIM * DIM);
    build_comb_kernel<<<(NWIN * NH * 64 * 64 + 255) / 256, 256, 0, stream>>>(bias_table, rel_idx, mask, comb);

    gemm256_kernel<true><<<dim3((M_TOTAL / 256) * (N_QKV / 256)), 512, 0, stream>>>(
        x_bf, wqkvT, b_qkv, qkv, N_QKV, DIM);

    attn_kernel<<<NBW * NH * 2 / 4, 256, 0, stream>>>(qkv, comb, attn_o);

    gemm256_kernel<false><<<dim3((M_TOTAL / 256) * (DIM / 256)), 512, 0, stream>>>(
        attn_o, wprojT, b_proj, out, DIM, DIM);
}

// Round 2
// 875.672 us; speedup vs baseline: 1.0728x; 1.0728x over previous
//
#include <hip/hip_runtime.h>
#include <hip/hip_bf16.h>
#include <stdint.h>

typedef float  floatx4 __attribute__((ext_vector_type(4)));
typedef short  short8  __attribute__((ext_vector_type(8)));
typedef unsigned short u16;

#define DIM 512
#define NH 16
#define HD 32
#define WS 49           // window size (tokens)
#define NBW 2048        // number of windows
#define NWIN 4          // mask groups
#define M_TOTAL (NBW*WS)    // 100352
#define N_QKV (3*DIM)       // 1536

// ---------- helpers ----------
__device__ __forceinline__ u16 f2bf(float f) {
    uint32_t u = __float_as_uint(f);
    u += 0x7FFFu + ((u >> 16) & 1u);   // RNE
    return (u16)(u >> 16);
}

__device__ __forceinline__ void load_lds16(const u16* g, u16* l) {
    __builtin_amdgcn_global_load_lds(
        (const __attribute__((address_space(1))) unsigned int*)g,
        (__attribute__((address_space(3))) unsigned int*)l, 16, 0, 0);
}

// ---------- cast x fp32 -> bf16 (vectorized) ----------
__global__ void cast_x_kernel(const float* __restrict__ in, u16* __restrict__ out, int n4) {
    int i = blockIdx.x * blockDim.x + threadIdx.x;
    if (i >= n4) return;
    const float4 v = ((const float4*)in)[i];
    ushort4 o;
    o.x = f2bf(v.x); o.y = f2bf(v.y); o.z = f2bf(v.z); o.w = f2bf(v.w);
    ((ushort4*)out)[i] = o;
}

// ---------- transpose + cast weight [K=512][N] -> Bt [N][512] bf16 ----------
__global__ void transpose_cast_kernel(const float* __restrict__ in, u16* __restrict__ out,
                                      int N, int total) {
    int idx = blockIdx.x * blockDim.x + threadIdx.x;   // idx = n*512 + k
    if (idx >= total) return;
    int k = idx & (DIM - 1);
    int n = idx >> 9;
    out[idx] = f2bf(in[k * N + n]);
}

// ---------- padded bias+mask table, permuted for float4 lane loads ----------
__global__ void build_comb_kernel(const float* __restrict__ bias_table, const int* __restrict__ rel_idx,
                                  const float* __restrict__ mask, float* __restrict__ comb) {
    int idx = blockIdx.x * blockDim.x + threadIdx.x;
    if (idx >= NWIN * NH * 64 * 64) return;
    int c = idx & 3, jj = (idx >> 2) & 15, i = (idx >> 6) & 63, h = (idx >> 12) & 15, g = idx >> 16;
    int j = c * 16 + jj;
    float v = -1e30f;
    if (i < WS && j < WS)
        v = bias_table[rel_idx[i * WS + j] * NH + h] + mask[(g * WS + i) * WS + j];
    comb[idx] = v;
}

// ---------- 256x256 8-phase MFMA GEMM, C = A[M][K] * Bt[N][K]^T + bias ----------
// 512 threads = 8 waves (2M x 4N), per-wave output 128x64.
// LDS: 2 dbuf x {A,B} x 2 K-halves x [256 rows][32 elems] bf16 = 128 KiB.
// XOR swizzle (T2, rule #21 both-sides): physical col = logical col ^ (((row>>1)&3)*8 elems).
//   - read side: cs = (q4 ^ ((lane>>1)&3)) * 8  -> start banks (rr&1)*16 + ((rr>>1&3)^q4)*4,
//     each bank hit 2x per 16 lanes = conflict-free ds_read_b128.
//   - stage side: LDS dest stays LINEAR (global_load_lds requirement); global SOURCE col
//     pre-swizzled by the same involution: 8*((tid&3) ^ ((tid>>3)&3)).
// Counted vmcnt(4) (T4); raw s_barrier (no drain); setprio around MFMA (T5); XCD swizzle (T1).
#define STAGE_HALF(BASE, DST, Q, KH, KCOL)                                            \
    do {                                                                              \
        load_lds16((BASE) + (long)(s0 >> 2) * K + (KCOL) + (KH) * 32 + ssw,           \
                   &DST[Q][KH][s0 * 8]);                                              \
        load_lds16((BASE) + (long)(s1 >> 2) * K + (KCOL) + (KH) * 32 + ssw,           \
                   &DST[Q][KH][s1 * 8]);                                              \
    } while (0)

#define LDA4(P, MG, KH)                                                               \
    _Pragma("unroll")                                                                 \
    for (int mi = 0; mi < 4; ++mi)                                                    \
        af[mi] = *(const short8*)(&sA[P][KH][(wm + (MG) * 64 + mi * 16 + rr) * 32 + cs]);

#define LDB4(P, KH)                                                                   \
    _Pragma("unroll")                                                                 \
    for (int ni = 0; ni < 4; ++ni)                                                    \
        bf[ni] = *(const short8*)(&sB[P][KH][(wn + ni * 16 + rr) * 32 + cs]);

#define MFMA16(MG)                                                                    \
    _Pragma("unroll")                                                                 \
    for (int mi = 0; mi < 4; ++mi)                                                    \
        _Pragma("unroll")                                                             \
        for (int ni = 0; ni < 4; ++ni)                                                \
            acc[(MG) * 4 + mi][ni] = __builtin_amdgcn_mfma_f32_16x16x32_bf16(         \
                af[mi], bf[ni], acc[(MG) * 4 + mi][ni], 0, 0, 0);

template<bool OUT_BF16>
__global__ __launch_bounds__(512, 2) void gemm256_kernel(
    const u16* __restrict__ A, const u16* __restrict__ Bt,
    const float* __restrict__ bias, void* __restrict__ out, int N, int K)
{
    __shared__ __align__(16) u16 sA[2][2][256 * 32];
    __shared__ __align__(16) u16 sB[2][2][256 * 32];

    const int tid  = threadIdx.x;
    const int lane = tid & 63;
    const int w    = tid >> 6;
    const int rr   = lane & 15;
    const int q4   = lane >> 4;
    const int wm   = (w >> 2) * 128;
    const int wn   = (w & 3) * 64;

    // swizzled LDS read column (elems): q4*8 XOR'd by row-derived bits (row&15 == rr)
    const int cs   = (q4 ^ ((lane >> 1) & 3)) * 8;
    // pre-swizzled global source column offset (elems) for linear-dest staging
    const int ssw  = ((tid & 3) ^ ((tid >> 3) & 3)) * 8;

    // bijective XCD-aware swizzle (gridDim.x is a multiple of 8: 2352 / 784)
    const int nwg = gridDim.x;
    const int lid = (blockIdx.x & 7) * (nwg >> 3) + (blockIdx.x >> 3);
    const int GX  = N >> 8;
    const int bx  = lid % GX;
    const int by  = lid / GX;
    const long m0 = (long)by * 256;
    const long n0 = (long)bx * 256;

    const u16* Ab = A  + m0 * K;
    const u16* Bb = Bt + n0 * K;

    const int s0 = tid;
    const int s1 = tid + 512;

    floatx4 acc[8][4];
    const floatx4 z4 = {0.f, 0.f, 0.f, 0.f};
#pragma unroll
    for (int i = 0; i < 8; ++i)
#pragma unroll
        for (int j = 0; j < 4; ++j) acc[i][j] = z4;

    const int nk = K >> 6;

    // prologue: stage tile0, retire order [A.kh0, B.kh0, A.kh1, B.kh1]
#pragma unroll
    for (int kh = 0; kh < 2; ++kh) {
        STAGE_HALF(Ab, sA, 0, kh, 0);
        STAGE_HALF(Bb, sB, 0, kh, 0);
    }
    asm volatile("s_waitcnt vmcnt(4)" ::: "memory");   // kh0 halves resident
    __builtin_amdgcn_s_barrier();

    for (int it = 0; it < nk; ++it) {
        const int  p  = it & 1, q = p ^ 1;
        const int  kn = (it + 1) << 6;                 // next tile k-col
        const bool hn = (it + 1 < nk);
        short8 af[4], bf[4];

        // ---- phase A: kh0 x m-group0 ----
        if (hn) STAGE_HALF(Ab, sA, q, 0, kn);
        LDB4(p, 0)
        LDA4(p, 0, 0)
        __builtin_amdgcn_s_barrier();
        __builtin_amdgcn_s_setprio(1);
        MFMA16(0)
        __builtin_amdgcn_s_setprio(0);
        __builtin_amdgcn_s_barrier();

        // ---- phase B: kh0 x m-group1 ----
        if (hn) STAGE_HALF(Bb, sB, q, 0, kn);
        LDA4(p, 1, 0)
        __builtin_amdgcn_s_barrier();
        __builtin_amdgcn_s_setprio(1);
        MFMA16(1)
        __builtin_amdgcn_s_setprio(0);
        if (hn) { asm volatile("s_waitcnt vmcnt(4)" ::: "memory"); }   // this tile's kh1 resident
        else    { asm volatile("s_waitcnt vmcnt(0)" ::: "memory"); }
        __builtin_amdgcn_s_barrier();

        // ---- phase C: kh1 x m-group0 ----
        if (hn) STAGE_HALF(Ab, sA, q, 1, kn);
        LDB4(p, 1)
        LDA4(p, 0, 1)
        __builtin_amdgcn_s_barrier();
        __builtin_amdgcn_s_setprio(1);
        MFMA16(0)
        __builtin_amdgcn_s_setprio(0);
        __builtin_amdgcn_s_barrier();

        // ---- phase D: kh1 x m-group1 ----
        if (hn) STAGE_HALF(Bb, sB, q, 1, kn);
        LDA4(p, 1, 1)
        __builtin_amdgcn_s_barrier();
        __builtin_amdgcn_s_setprio(1);
        MFMA16(1)
        __builtin_amdgcn_s_setprio(0);
        if (hn) { asm volatile("s_waitcnt vmcnt(4)" ::: "memory"); }   // next tile's kh0 resident
        __builtin_amdgcn_s_barrier();
    }

    // epilogue: per (row, r) emit the 4 nf chunks back-to-back so each wave's
    // 4x32B chunks of one 128B line merge in L2.
    float bv[4];
#pragma unroll
    for (int nf = 0; nf < 4; ++nf) bv[nf] = bias[n0 + wn + nf * 16 + rr];
#pragma unroll
    for (int mf = 0; mf < 8; ++mf) {
        const long mrow = m0 + wm + mf * 16 + q4 * 4;
#pragma unroll
        for (int r = 0; r < 4; ++r) {
            const long m = mrow + r;
#pragma unroll
            for (int nf = 0; nf < 4; ++nf) {
                const long n = n0 + wn + nf * 16 + rr;
                const float v = acc[mf][nf][r] + bv[nf];
                if (OUT_BF16) ((u16*)out)[m * N + n] = f2bf(v);
                else          ((float*)out)[m * N + n] = v;
            }
        }
    }
}

// ---------- attention v3: one wave per (window, head, 32-row half) ----------
__global__ __launch_bounds__(256, 4) void attn_kernel(
    const u16* __restrict__ qkv, const float* __restrict__ comb,
    u16* __restrict__ attn_out)
{
    const int w   = threadIdx.x >> 6;
    const int l   = threadIdx.x & 63;
    const int job = blockIdx.x * 4 + w;          // job = b*32 + h*2 + half
    const int b    = job >> 5;
    const int h    = (job >> 1) & 15;
    const int half = job & 1;
    const int row0 = half * 32;
    const int rr = l & 15;
    const int q4 = l >> 4;
    const int qk = q4 * 8;

    __shared__ __align__(16) u16 p_s[4][32 * 64];
    u16* ps = p_s[w];

    const u16* qg = qkv + (long)b * WS * N_QKV + h * HD;
    const u16* kg = qg + DIM;
    const u16* vg = qg + 2 * DIM;

    const short8 z8 = {0, 0, 0, 0, 0, 0, 0, 0};
    const floatx4 z4 = {0.f, 0.f, 0.f, 0.f};

    short8 af[2], bfr[4];
#pragma unroll
    for (int mi = 0; mi < 2; ++mi) {
        const int row = row0 + mi * 16 + rr;
        af[mi] = (row < WS) ? *(const short8*)(qg + (long)row * N_QKV + qk) : z8;
    }
#pragma unroll
    for (int ni = 0; ni < 4; ++ni) {
        const int row = ni * 16 + rr;
        bfr[ni] = (row < WS) ? *(const short8*)(kg + (long)row * N_QKV + qk) : z8;
    }

    short8 vf[2][2];
#pragma unroll
    for (int kk = 0; kk < 2; ++kk)
#pragma unroll
        for (int ni = 0; ni < 2; ++ni) {
            short8 t = z8;
            const int d = 2 * rr + ni;
#pragma unroll
            for (int j = 0; j < 8; ++j) {
                const int s = kk * 32 + qk + j;
                if (s < WS) t[j] = (short)vg[(long)s * N_QKV + d];
            }
            vf[kk][ni] = t;
        }
    short8 vones;
#pragma unroll
    for (int j = 0; j < 8; ++j) vones[j] = (short)0x3F80;

    floatx4 sc[2][4];
#pragma unroll
    for (int mi = 0; mi < 2; ++mi)
#pragma unroll
        for (int ni = 0; ni < 4; ++ni)
            sc[mi][ni] = __builtin_amdgcn_mfma_f32_16x16x32_bf16(af[mi], bfr[ni], z4, 0, 0, 0);

    const float4* cb4 = (const float4*)comb + ((long)((b & (NWIN - 1)) * NH + h)) * 1024;
    const float scale = 0.17677669529663689f;   // 32^-0.5
#pragma unroll
    for (int mi = 0; mi < 2; ++mi) {
#pragma unroll
        for (int r = 0; r < 4; ++r) {
            const int il = mi * 16 + q4 * 4 + r;       // local row 0..31
            const float4 cb = cb4[(row0 + il) * 16 + rr];
            float e0 = __expf(sc[mi][0][r] * scale + cb.x);
            float e1 = __expf(sc[mi][1][r] * scale + cb.y);
            float e2 = __expf(sc[mi][2][r] * scale + cb.z);
            float e3 = __expf(sc[mi][3][r] * scale + cb.w);
#pragma unroll
            for (int c = 0; c < 4; ++c) {
                const int col = c * 16 + rr;
                const int blk = (col >> 3) ^ (il & 7);
                const float ev = (c == 0) ? e0 : (c == 1) ? e1 : (c == 2) ? e2 : e3;
                ps[il * 64 + blk * 8 + (col & 7)] = f2bf(ev);
            }
        }
    }
    asm volatile("s_waitcnt lgkmcnt(0)" ::: "memory");

    floatx4 oacc[2][3];
#pragma unroll
    for (int mi = 0; mi < 2; ++mi) { oacc[mi][0] = z4; oacc[mi][1] = z4; oacc[mi][2] = z4; }
#pragma unroll
    for (int kk = 0; kk < 2; ++kk) {
        short8 pf[2];
#pragma unroll
        for (int mi = 0; mi < 2; ++mi) {
            const int i2 = mi * 16 + rr;
            pf[mi] = *(const short8*)(ps + i2 * 64 + (((4 * kk + q4) ^ (i2 & 7)) * 8));
        }
#pragma unroll
        for (int mi = 0; mi < 2; ++mi) {
            oacc[mi][0] = __builtin_amdgcn_mfma_f32_16x16x32_bf16(pf[mi], vf[kk][0], oacc[mi][0], 0, 0, 0);
            oacc[mi][1] = __builtin_amdgcn_mfma_f32_16x16x32_bf16(pf[mi], vf[kk][1], oacc[mi][1], 0, 0, 0);
            oacc[mi][2] = __builtin_amdgcn_mfma_f32_16x16x32_bf16(pf[mi], vones,     oacc[mi][2], 0, 0, 0);
        }
    }

#pragma unroll
    for (int mi = 0; mi < 2; ++mi) {
#pragma unroll
        for (int r = 0; r < 4; ++r) {
            const int ig = row0 + mi * 16 + q4 * 4 + r;
            if (ig < WS) {
                const float inv = 1.0f / oacc[mi][2][r];
                const uint32_t lo = f2bf(oacc[mi][0][r] * inv);
                const uint32_t hi = f2bf(oacc[mi][1][r] * inv);
                uint32_t* op = (uint32_t*)(attn_out + ((long)(b * WS + ig)) * DIM + h * HD);
                op[rr] = lo | (hi << 16);
            }
        }
    }
}

// ---------- launch ----------
extern "C" void kernel_launch(void* const* d_in, const int* in_sizes, int n_in,
                              void* d_out, int out_size, void* d_ws, size_t ws_size,
                              hipStream_t stream)
{
    const float* x          = (const float*)d_in[0];
    const float* mask       = (const float*)d_in[1];
    const float* w_qkv      = (const float*)d_in[2];
    const float* b_qkv      = (const float*)d_in[3];
    const float* w_proj     = (const float*)d_in[4];
    const float* b_proj     = (const float*)d_in[5];
    const float* bias_table = (const float*)d_in[6];
    const int*   rel_idx    = (const int*)d_in[7];
    float* out = (float*)d_out;

    char* ws = (char*)d_ws;
    u16* x_bf   = (u16*)ws;  ws += (size_t)M_TOTAL * DIM * 2;        // 102.8 MB (reused as attn_out)
    u16* wqkvT  = (u16*)ws;  ws += (size_t)N_QKV * DIM * 2;          // 1.5 MB
    u16* wprojT = (u16*)ws;  ws += (size_t)DIM * DIM * 2;            // 0.5 MB
    float* comb = (float*)ws; ws += (size_t)NWIN * NH * 64 * 64 * 4; // 1.0 MB
    u16* qkv    = (u16*)ws;  ws += (size_t)M_TOTAL * N_QKV * 2;      // 308.3 MB
    u16* attn_o = x_bf;   // alias: x_bf dead after GEMM1

    const int n4 = M_TOTAL * DIM / 4;
    cast_x_kernel<<<(n4 + 255) / 256, 256, 0, stream>>>(x, x_bf, n4);
    transpose_cast_kernel<<<(N_QKV * DIM + 255) / 256, 256, 0, stream>>>(w_qkv, wqkvT, N_QKV, N_QKV * DIM);
    transpose_cast_kernel<<<(DIM * DIM + 255) / 256, 256, 0, stream>>>(w_proj, wprojT, DIM, DIM * DIM);
    build_comb_kernel<<<(NWIN * NH * 64 * 64 + 255) / 256, 256, 0, stream>>>(bias_table, rel_idx, mask, comb);

    gemm256_kernel<true><<<dim3((M_TOTAL / 256) * (N_QKV / 256)), 512, 0, stream>>>(
        x_bf, wqkvT, b_qkv, qkv, N_QKV, DIM);

    attn_kernel<<<NBW * NH * 2 / 4, 256, 0, stream>>>(qkv, comb, attn_o);

    gemm256_kernel<false><<<dim3((M_TOTAL / 256) * (DIM / 256)), 512, 0, stream>>>(
        attn_o, wprojT, b_proj, out, DIM, DIM);
}

// Round 4
// 784.267 us; speedup vs baseline: 1.1978x; 1.1165x over previous
//
#include <hip/hip_runtime.h>
#include <hip/hip_bf16.h>
#include <stdint.h>

typedef float  floatx4 __attribute__((ext_vector_type(4)));
typedef short  short8  __attribute__((ext_vector_type(8)));
typedef unsigned short u16;

#define DIM 512
#define NH 16
#define HD 32
#define WS 49           // window size (tokens)
#define NBW 2048        // number of windows
#define NWIN 4          // mask groups
#define M_TOTAL (NBW*WS)    // 100352
#define N_QKV (3*DIM)       // 1536

// ---------- helpers ----------
__device__ __forceinline__ u16 f2bf(float f) {
    uint32_t u = __float_as_uint(f);
    u += 0x7FFFu + ((u >> 16) & 1u);   // RNE
    return (u16)(u >> 16);
}

__device__ __forceinline__ void load_lds16(const u16* g, u16* l) {
    __builtin_amdgcn_global_load_lds(
        (const __attribute__((address_space(1))) unsigned int*)g,
        (__attribute__((address_space(3))) unsigned int*)l, 16, 0, 0);
}

// ---------- cast x fp32 -> bf16 (vectorized) ----------
__global__ void cast_x_kernel(const float* __restrict__ in, u16* __restrict__ out, int n4) {
    int i = blockIdx.x * blockDim.x + threadIdx.x;
    if (i >= n4) return;
    const float4 v = ((const float4*)in)[i];
    ushort4 o;
    o.x = f2bf(v.x); o.y = f2bf(v.y); o.z = f2bf(v.z); o.w = f2bf(v.w);
    ((ushort4*)out)[i] = o;
}

// ---------- coalesced transpose + cast: [K=512][N] f32 -> [N][512] bf16 ----------
__global__ void transpose_cast_kernel(const float* __restrict__ in, u16* __restrict__ out, int N) {
    __shared__ float t[32][33];
    const int bx = blockIdx.x * 32;           // n block
    const int by = blockIdx.y * 32;           // k block
    const int lx = threadIdx.x & 31;
    const int ly = threadIdx.x >> 5;          // 0..7
#pragma unroll
    for (int i = 0; i < 32; i += 8)
        t[ly + i][lx] = in[(long)(by + ly + i) * N + bx + lx];
    __syncthreads();
#pragma unroll
    for (int i = 0; i < 32; i += 8)
        out[(long)(bx + ly + i) * 512 + by + lx] = f2bf(t[lx][ly + i]);
}

// ---------- padded bias+mask table, permuted for float4 lane loads ----------
// comb[(((g*16+h)*64 + i)*16 + jj)*4 + c] = value(row i, col c*16+jj), pad = -1e30
__global__ void build_comb_kernel(const float* __restrict__ bias_table, const int* __restrict__ rel_idx,
                                  const float* __restrict__ mask, float* __restrict__ comb) {
    int idx = blockIdx.x * blockDim.x + threadIdx.x;
    if (idx >= NWIN * NH * 64 * 64) return;
    int c = idx & 3, jj = (idx >> 2) & 15, i = (idx >> 6) & 63, h = (idx >> 12) & 15, g = idx >> 16;
    int j = c * 16 + jj;
    float v = -1e30f;
    if (i < WS && j < WS)
        v = bias_table[rel_idx[i * WS + j] * NH + h] + mask[(g * WS + i) * WS + j];
    comb[idx] = v;
}

// ---------- 128x128 MFMA GEMM, C = A[M][K] * Bt[N][K]^T + bias ----------
// r0 structure (proven 246us) + two individually-verified grafts:
//  - cs/ssw XOR swizzle pair (r2: conflicts 1.44e7 -> 0; same 32-elem row layout):
//    read col cs = (rq ^ ((lane>>1)&3))*8; staging global SOURCE col pre-swizzled
//    ssw = ((tid&3)^((tid>>3)&3))*8, LDS dest linear (global_load_lds requirement).
//  - flat bijective XCD-aware block swizzle (r2: FETCH 408->105MB; nwg%8==0).
template<bool OUT_BF16>
__global__ __launch_bounds__(256, 2) void gemm_bt_kernel(
    const u16* __restrict__ A, const u16* __restrict__ Bt,
    const float* __restrict__ bias, void* __restrict__ out, int N, int K)
{
    __shared__ __align__(16) u16 sA[128 * 32];
    __shared__ __align__(16) u16 sB[128 * 32];
    const int tid  = threadIdx.x;
    const int lane = tid & 63;
    const int wave = tid >> 6;

    // flat bijective XCD swizzle (gridDim.x*gridDim.y % 8 == 0: 9408 / 3136)
    const int GXd = gridDim.x;
    const int nwg = GXd * gridDim.y;
    int fb = blockIdx.y * GXd + blockIdx.x;
    fb = (fb & 7) * (nwg >> 3) + (fb >> 3);
    const long m0 = (long)(fb / GXd) * 128;
    const long n0 = (long)(fb % GXd) * 128;

    const int rr = lane & 15;
    const int rq = lane >> 4;
    const int cs = (rq ^ ((lane >> 1) & 3)) * 8;   // swizzled LDS read col (elems)
    const int wm = (wave >> 1) * 64;
    const int wn = (wave & 1) * 64;

    floatx4 acc[4][4];
    const floatx4 z4 = {0.f, 0.f, 0.f, 0.f};
#pragma unroll
    for (int mi = 0; mi < 4; ++mi)
#pragma unroll
        for (int ni = 0; ni < 4; ++ni) acc[mi][ni] = z4;

    const int row0 = tid >> 2;
    const int ssw  = ((tid & 3) ^ ((tid >> 3) & 3)) * 8;  // pre-swizzled source col
    const u16* gA0 = A  + (m0 + row0) * K + ssw;
    const u16* gA1 = A  + (m0 + row0 + 64) * K + ssw;
    const u16* gB0 = Bt + (n0 + row0) * K + ssw;
    const u16* gB1 = Bt + (n0 + row0 + 64) * K + ssw;
    u16* lA0 = sA + tid * 8;
    u16* lA1 = sA + (tid + 256) * 8;
    u16* lB0 = sB + tid * 8;
    u16* lB1 = sB + (tid + 256) * 8;

    for (int k0 = 0; k0 < K; k0 += 32) {
        load_lds16(gA0 + k0, lA0);
        load_lds16(gA1 + k0, lA1);
        load_lds16(gB0 + k0, lB0);
        load_lds16(gB1 + k0, lB1);
        __syncthreads();
        short8 af[4], bfr[4];
#pragma unroll
        for (int mi = 0; mi < 4; ++mi)
            af[mi] = *(const short8*)(sA + (wm + mi * 16 + rr) * 32 + cs);
#pragma unroll
        for (int ni = 0; ni < 4; ++ni)
            bfr[ni] = *(const short8*)(sB + (wn + ni * 16 + rr) * 32 + cs);
#pragma unroll
        for (int mi = 0; mi < 4; ++mi)
#pragma unroll
            for (int ni = 0; ni < 4; ++ni)
                acc[mi][ni] = __builtin_amdgcn_mfma_f32_16x16x32_bf16(af[mi], bfr[ni], acc[mi][ni], 0, 0, 0);
        __syncthreads();
    }

#pragma unroll
    for (int mi = 0; mi < 4; ++mi) {
#pragma unroll
        for (int r = 0; r < 4; ++r) {
            const long m = m0 + wm + mi * 16 + rq * 4 + r;
#pragma unroll
            for (int ni = 0; ni < 4; ++ni) {
                const long n = n0 + wn + ni * 16 + rr;
                float v = acc[mi][ni][r] + bias[n];
                if (OUT_BF16) ((u16*)out)[m * N + n] = f2bf(v);
                else          ((float*)out)[m * N + n] = v;
            }
        }
    }
}

// ---------- attention v4: one wave per (window, head) -- merged halves ----------
// vs v3: K/V/comb fragments loaded ONCE per (b,h) instead of twice (two half-jobs)
// -> -262MB HBM, -50% scalar V gathers, half the jobs. Q covers rows 0..63 in 4
// row-tiles (rows>=49 masked to 0; padded comb rows give exp(-1e30)=0, no NaN).
__global__ __launch_bounds__(256, 4) void attn_kernel(
    const u16* __restrict__ qkv, const float* __restrict__ comb,
    u16* __restrict__ attn_out)
{
    const int w   = threadIdx.x >> 6;
    const int l   = threadIdx.x & 63;
    const int job = blockIdx.x * 4 + w;          // job = b*16 + h
    const int b   = job >> 4;
    const int h   = job & 15;
    const int rr = l & 15;
    const int q4 = l >> 4;
    const int qk = q4 * 8;

    __shared__ __align__(16) u16 p_s[4][64 * 64];   // 32 KB
    u16* ps = p_s[w];

    const u16* qg = qkv + (long)b * WS * N_QKV + h * HD;
    const u16* kg = qg + DIM;
    const u16* vg = qg + 2 * DIM;

    const short8 z8 = {0, 0, 0, 0, 0, 0, 0, 0};
    const floatx4 z4 = {0.f, 0.f, 0.f, 0.f};

    // K B-frags (full 64 cols), loaded once
    short8 bfr[4];
#pragma unroll
    for (int ni = 0; ni < 4; ++ni) {
        const int row = ni * 16 + rr;
        bfr[ni] = (row < WS) ? *(const short8*)(kg + (long)row * N_QKV + qk) : z8;
    }

    // V^T B-frags, columns interleaved: tile0 -> d=2*rr (even), tile1 -> d=2*rr+1 (odd)
    short8 vf[2][2];
#pragma unroll
    for (int kk = 0; kk < 2; ++kk)
#pragma unroll
        for (int ni = 0; ni < 2; ++ni) {
            short8 t = z8;
            const int d = 2 * rr + ni;
#pragma unroll
            for (int j = 0; j < 8; ++j) {
                const int s = kk * 32 + qk + j;
                if (s < WS) t[j] = (short)vg[(long)s * N_QKV + d];
            }
            vf[kk][ni] = t;
        }
    // all-ones B-tile for row sums (bf16 1.0 = 0x3F80)
    short8 vones;
#pragma unroll
    for (int j = 0; j < 8; ++j) vones[j] = (short)0x3F80;

    // Q A-frags: 4 row-tiles (rows 0..63, masked >= WS)
    short8 af[4];
#pragma unroll
    for (int mi = 0; mi < 4; ++mi) {
        const int row = mi * 16 + rr;
        af[mi] = (row < WS) ? *(const short8*)(qg + (long)row * N_QKV + qk) : z8;
    }

    const float4* cb4 = (const float4*)comb + ((long)((b & (NWIN - 1)) * NH + h)) * 1024;
    const float scale = 0.17677669529663689f;   // 32^-0.5

    // QK^T + max-free softmax numerator -> p_s (XOR-swizzled 16B blocks), per row-tile
#pragma unroll
    for (int mi = 0; mi < 4; ++mi) {
        floatx4 scm[4];
#pragma unroll
        for (int ni = 0; ni < 4; ++ni)
            scm[ni] = __builtin_amdgcn_mfma_f32_16x16x32_bf16(af[mi], bfr[ni], z4, 0, 0, 0);
#pragma unroll
        for (int r = 0; r < 4; ++r) {
            const int il = mi * 16 + q4 * 4 + r;       // row 0..63
            const float4 cb = cb4[il * 16 + rr];
            float e0 = __expf(scm[0][r] * scale + cb.x);
            float e1 = __expf(scm[1][r] * scale + cb.y);
            float e2 = __expf(scm[2][r] * scale + cb.z);
            float e3 = __expf(scm[3][r] * scale + cb.w);
#pragma unroll
            for (int c = 0; c < 4; ++c) {
                const int col = c * 16 + rr;
                const int blk = (col >> 3) ^ (il & 7);
                const float ev = (c == 0) ? e0 : (c == 1) ? e1 : (c == 2) ? e2 : e3;
                ps[il * 64 + blk * 8 + (col & 7)] = f2bf(ev);
            }
        }
    }
    // same-wave LDS ordering: drain writes before reads (no cross-wave dependence)
    asm volatile("s_waitcnt lgkmcnt(0)" ::: "memory");

    // PV + row-sum: O[64][32] = P[64][64] @ V'[64][32], sums in slot 2
    floatx4 oacc[4][3];
#pragma unroll
    for (int mi = 0; mi < 4; ++mi) { oacc[mi][0] = z4; oacc[mi][1] = z4; oacc[mi][2] = z4; }
#pragma unroll
    for (int kk = 0; kk < 2; ++kk) {
        short8 pf[4];
#pragma unroll
        for (int mi = 0; mi < 4; ++mi) {
            const int i2 = mi * 16 + rr;
            pf[mi] = *(const short8*)(ps + i2 * 64 + (((4 * kk + q4) ^ (i2 & 7)) * 8));
        }
#pragma unroll
        for (int mi = 0; mi < 4; ++mi) {
            oacc[mi][0] = __builtin_amdgcn_mfma_f32_16x16x32_bf16(pf[mi], vf[kk][0], oacc[mi][0], 0, 0, 0);
            oacc[mi][1] = __builtin_amdgcn_mfma_f32_16x16x32_bf16(pf[mi], vf[kk][1], oacc[mi][1], 0, 0, 0);
            oacc[mi][2] = __builtin_amdgcn_mfma_f32_16x16x32_bf16(pf[mi], vones,     oacc[mi][2], 0, 0, 0);
        }
    }

    // epilogue: normalize, pack d=2rr,2rr+1 into one u32 store
#pragma unroll
    for (int mi = 0; mi < 4; ++mi) {
#pragma unroll
        for (int r = 0; r < 4; ++r) {
            const int ig = mi * 16 + q4 * 4 + r;
            if (ig < WS) {
                const float inv = 1.0f / oacc[mi][2][r];
                const uint32_t lo = f2bf(oacc[mi][0][r] * inv);
                const uint32_t hi = f2bf(oacc[mi][1][r] * inv);
                uint32_t* op = (uint32_t*)(attn_out + ((long)(b * WS + ig)) * DIM + h * HD);
                op[rr] = lo | (hi << 16);
            }
        }
    }
}

// ---------- launch ----------
extern "C" void kernel_launch(void* const* d_in, const int* in_sizes, int n_in,
                              void* d_out, int out_size, void* d_ws, size_t ws_size,
                              hipStream_t stream)
{
    const float* x          = (const float*)d_in[0];
    const float* mask       = (const float*)d_in[1];
    const float* w_qkv      = (const float*)d_in[2];
    const float* b_qkv      = (const float*)d_in[3];
    const float* w_proj     = (const float*)d_in[4];
    const float* b_proj     = (const float*)d_in[5];
    const float* bias_table = (const float*)d_in[6];
    const int*   rel_idx    = (const int*)d_in[7];
    float* out = (float*)d_out;

    char* ws = (char*)d_ws;
    u16* x_bf   = (u16*)ws;  ws += (size_t)M_TOTAL * DIM * 2;        // 102.8 MB (reused as attn_out)
    u16* wqkvT  = (u16*)ws;  ws += (size_t)N_QKV * DIM * 2;          // 1.5 MB
    u16* wprojT = (u16*)ws;  ws += (size_t)DIM * DIM * 2;            // 0.5 MB
    float* comb = (float*)ws; ws += (size_t)NWIN * NH * 64 * 64 * 4; // 1.0 MB
    u16* qkv    = (u16*)ws;  ws += (size_t)M_TOTAL * N_QKV * 2;      // 308.3 MB
    u16* attn_o = x_bf;   // alias: x_bf dead after GEMM1

    const int n4 = M_TOTAL * DIM / 4;
    cast_x_kernel<<<(n4 + 255) / 256, 256, 0, stream>>>(x, x_bf, n4);
    transpose_cast_kernel<<<dim3(N_QKV / 32, 16), 256, 0, stream>>>(w_qkv, wqkvT, N_QKV);
    transpose_cast_kernel<<<dim3(DIM / 32, 16), 256, 0, stream>>>(w_proj, wprojT, DIM);
    build_comb_kernel<<<(NWIN * NH * 64 * 64 + 255) / 256, 256, 0, stream>>>(bias_table, rel_idx, mask, comb);

    gemm_bt_kernel<true><<<dim3(N_QKV / 128, M_TOTAL / 128), 256, 0, stream>>>(
        x_bf, wqkvT, b_qkv, qkv, N_QKV, DIM);

    attn_kernel<<<NBW * NH / 4, 256, 0, stream>>>(qkv, comb, attn_o);

    gemm_bt_kernel<false><<<dim3(DIM / 128, M_TOTAL / 128), 256, 0, stream>>>(
        attn_o, wprojT, b_proj, out, DIM, DIM);
}